// Round 9
// baseline (1099.140 us; speedup 1.0000x reference)
//
#include <hip/hip_runtime.h>
#include <hip/hip_bf16.h>

#define NB 8
#define C 256
#define LL 6400
#define HEADS 8
#define HC 32
#define NH 64      // NB*HEADS
#define SEG 40     // ctx l-segments
#define SL 160     // LL / SEG
#define QPP 264    // out Q-panel pitch (u16)

typedef unsigned short u16;
typedef unsigned int u32;
typedef __attribute__((ext_vector_type(8))) short bf16x8;
typedef __attribute__((ext_vector_type(4))) float f32x4;

typedef __attribute__((address_space(1))) const u32 ga_u32;
typedef __attribute__((address_space(3))) u32 ls_u32;

__device__ __forceinline__ void gload_lds16(const u16* g, u16* l) {
  __builtin_amdgcn_global_load_lds((ga_u32*)g, (ls_u32*)l, 16, 0, 0);
}

__device__ __forceinline__ float bf2f(u32 u) { return __uint_as_float(u << 16); }
__device__ __forceinline__ u16 f2bf(float f) {
  __hip_bfloat16 h = __float2bfloat16(f);
  return *(u16*)&h;
}
__device__ __forceinline__ void unpack8(uint4 u, float* f) {
  f[0] = bf2f(u.x & 0xffffu); f[1] = bf2f(u.x >> 16);
  f[2] = bf2f(u.y & 0xffffu); f[3] = bf2f(u.y >> 16);
  f[4] = bf2f(u.z & 0xffffu); f[5] = bf2f(u.z >> 16);
  f[6] = bf2f(u.w & 0xffffu); f[7] = bf2f(u.w >> 16);
}

struct WcvtArgs { const float* W[3]; u16* Wb[3]; };
struct PFArgs { const float* X[3]; const u16* Wb[3]; const float* bias[3]; u16* P[3]; };

// ---- W fp32 -> bf16, chunk-swizzled within each 32-c window: v ^= (co>>1)&3 ----
// (verified) Kills the 8-way Bs bank conflict of the linear layout.
__global__ __launch_bounds__(256) void wcvt(WcvtArgs a) {
  const int idx = blockIdx.x * 256 + threadIdx.x;  // < 3*256*32 chunks
  const int which = idx >> 13, r = idx & 8191;
  const int co = r >> 5, c8 = r & 31;
  const float* src = a.W[which] + co * 256 + c8 * 8;
  float4 v0 = *(const float4*)src, v1 = *(const float4*)(src + 4);
  union { bf16x8 v; u16 h[8]; } o;
  o.h[0] = f2bf(v0.x); o.h[1] = f2bf(v0.y); o.h[2] = f2bf(v0.z); o.h[3] = f2bf(v0.w);
  o.h[4] = f2bf(v1.x); o.h[5] = f2bf(v1.y); o.h[6] = f2bf(v1.z); o.h[7] = f2bf(v1.w);
  const int p = (c8 & ~3) | ((c8 & 3) ^ ((co >> 1) & 3));
  *(bf16x8*)&a.Wb[which][co * 256 + p * 8] = o.v;
}

// ------- proj (x3, transpose fused IN-LDS): Pt[l][co] = sum_c X[c][l]*W[co][c]+b -------
// R9: BW-duty-cycle fix. R8's preamble was stop-and-go (issue 4KB -> full-drain
// barrier immediately): achieved BW = in-flight/latency x duty-cycle ~= 1.67
// TB/s, which retrodicts EVERY prior round (1.6-2.3). Key: each wave transposes
// exactly the rows it stages -> NO cross-wave dep in the preamble -> all 8
// preamble barriers deleted. X split into 8 eighths [32c][64l] (8 KB),
// Xs double-buffered, per-wave counted vmcnt(2): stage e+2 always in flight
// while transposing e (issue-to-drain gap = full transpose phase).
// k-loop/W-path/epilogue byte-identical to R8 (verified). LDS 80 KB, 2 blk/CU.
__global__ __launch_bounds__(256, 2) void proj_fused(PFArgs args) {
  __shared__ __align__(16) float Xs[2][32 * 64];  // eighth stage dbuf, 2x8 KB
  __shared__ __align__(16) u16 Ap[64 * 256];      // A panel [l][c] bf16, 32 KB; epilogue reuses
  __shared__ __align__(16) u16 Bs[2][256 * 32];   // W dbuf, 32 KB
  const int which = blockIdx.y >> 3, n = blockIdx.y & 7;
  const int l0 = blockIdx.x * 64;
  const int t = threadIdx.x;
  const int lane = t & 63, wave = t >> 6;
  const int fr = lane & 15, q = lane >> 4;
  const int wl = (wave & 1) * 32, wco = (wave >> 1) * 128;
  const int srow = t >> 2, scol = (t & 3) * 8;  // B staging coords
  const float* X = args.X[which] + (size_t)n * C * LL;
  const u16* Wb = args.Wb[which];
  const int xr = lane >> 4, xc = (lane & 15) * 4;  // X stage per-lane coords

  // B tile 0 (oldest VM ops; forced complete by the first preamble vmcnt)
#pragma unroll
  for (int s = 0; s < 4; ++s)
    gload_lds16(&Wb[(size_t)(s * 64 + srow) * C + scol], &Bs[0][s * 2048 + wave * 512]);

  // ---- preamble: 8 eighths, per-wave pipelined, ZERO barriers ----
  // stage(e): wave stages its own c-rows 32e+8w .. +7 (2 gloads)
#define PF_STAGE(e)                                                                  \
  {                                                                                  \
    _Pragma("unroll")                                                                \
    for (int s = 0; s < 2; ++s)                                                      \
      gload_lds16((const u16*)&X[(size_t)(32 * (e) + wave * 8 + s * 4 + xr) * LL +   \
                                 l0 + xc],                                           \
                  (u16*)&Xs[(e) & 1][(wave * 8 + s * 4) * 64]);                      \
  }
  PF_STAGE(0)
  PF_STAGE(1)
#pragma unroll
  for (int e = 0; e < 8; ++e) {
    if (e < 7) { asm volatile("s_waitcnt vmcnt(2)" ::: "memory"); }
    else       { asm volatile("s_waitcnt vmcnt(0)" ::: "memory"); }
    // transpose own 8 rows of eighth e: chunk cb = 4e + wave
    float v[8];
#pragma unroll
    for (int ei = 0; ei < 8; ++ei) v[ei] = Xs[e & 1][(wave * 8 + ei) * 64 + lane];
    union { uint4 u; u32 w[4]; } pk;
#pragma unroll
    for (int p = 0; p < 4; ++p)
      pk.w[p] = (u32)f2bf(v[2 * p]) | ((u32)f2bf(v[2 * p + 1]) << 16);
    const int cb = e * 4 + wave;
    *(uint4*)&Ap[lane * 256 + ((cb ^ (lane & 7)) * 8)] = pk.u;
    if (e < 6) {
      // own ds_reads of Xs[e&1] retired before restaging it (rule #18 fence)
      asm volatile("s_waitcnt lgkmcnt(0)" ::: "memory");
      __builtin_amdgcn_sched_barrier(0);
      PF_STAGE(e + 2)
    }
  }
#undef PF_STAGE
  __syncthreads();  // Ap + Bs[0] visible to all waves

  // ---- k-loop: identical to R8 (verified) ----
  f32x4 acc[2][8] = {};
  const int sco = (fr >> 1) & 3;  // W chunk swizzle key
#pragma unroll
  for (int kt = 0; kt < 8; ++kt) {
    if (kt < 7) {
#pragma unroll
      for (int s = 0; s < 4; ++s)
        gload_lds16(&Wb[(size_t)(s * 64 + srow) * C + (kt + 1) * 32 + scol],
                    &Bs[(kt + 1) & 1][s * 2048 + wave * 512]);
    }
    bf16x8 a[2];
#pragma unroll
    for (int i = 0; i < 2; ++i) {
      const int row = wl + i * 16 + fr;
      a[i] = *(const bf16x8*)&Ap[row * 256 + (((kt * 4 + q) ^ (row & 7)) * 8)];
    }
#pragma unroll
    for (int j = 0; j < 8; ++j) {
      bf16x8 b = *(const bf16x8*)&Bs[kt & 1][(wco + j * 16 + fr) * 32 + ((q ^ sco) * 8)];
#pragma unroll
      for (int i = 0; i < 2; ++i)
        acc[i][j] = __builtin_amdgcn_mfma_f32_16x16x32_bf16(a[i], b, acc[i][j], 0, 0, 0);
    }
    __syncthreads();  // next Bs tile complete; buffers ping-pong safely
  }

  // ---- epilogue: identical to R8 (verified), reuse Ap ----
  const float* bias = args.bias[which];
  u16* P = args.P[which] + (size_t)n * LL * C;
  float bb[8];
#pragma unroll
  for (int j = 0; j < 8; ++j) bb[j] = bias[wco + j * 16 + fr];
#pragma unroll
  for (int i = 0; i < 2; ++i)
#pragma unroll
    for (int r = 0; r < 4; ++r) {
      const int lrow = wl + i * 16 + q * 4 + r;  // 0..63 block-local
#pragma unroll
      for (int j = 0; j < 8; ++j)
        Ap[lrow * 256 + wco + j * 16 + fr] = f2bf(acc[i][j][r] + bb[j]);
    }
  __syncthreads();
  const int rg = t >> 5, ch = t & 31;  // row group, 16B chunk
#pragma unroll
  for (int s = 0; s < 8; ++s) {
    const int row = rg * 8 + s;
    bf16x8 vrow = *(const bf16x8*)&Ap[row * 256 + ch * 8];
    *(bf16x8*)&P[(size_t)(l0 + row) * C + ch * 8] = vrow;  // 512B/row, full lines
  }
}

// -------- ctx partials (one pass, no-max softmax): pctx += exp(K)[l,k]*V[l,v] --------
// grid (SEG, NB). R9: K/V double-buffered with counted vmcnt(4) + raw barriers
// (no full drains). Old code issued its 8 KB stage and drained it at the very
// next instruction (zero issue-to-drain gap); now stage(it+1) flies under the
// whole ~2K-cycle compute(it) phase.
__global__ __launch_bounds__(256) void ctx_part(const u16* __restrict__ Kt,
    const u16* __restrict__ Vt, float* __restrict__ pctx, float* __restrict__ psum) {
  __shared__ __align__(16) u16 Ks[2][16 * 256];
  __shared__ __align__(16) u16 Vs[2][16 * 256];
  const int seg = blockIdx.x, n = blockIdx.y;
  const int t = threadIdx.x, lane = t & 63, wave = t >> 6;
  const int l0 = seg * SL;
  const u16* KtN = Kt + (size_t)n * LL * C;
  const u16* VtN = Vt + (size_t)n * LL * C;
  const int k4 = (lane & 7) * 4, v8 = lane >> 3;
  float acc[2][4][4] = {};
  float ssum[2][4] = {};

#define CP_STAGE(it)                                                              \
  {                                                                               \
    _Pragma("unroll")                                                             \
    for (int i = 0; i < 2; ++i) {                                                 \
      const int r = wave * 4 + i * 2;                                             \
      gload_lds16(&KtN[(size_t)(l0 + (it) * 16 + r) * C + lane * 8],              \
                  &Ks[(it) & 1][r * 256]);                                        \
      gload_lds16(&VtN[(size_t)(l0 + (it) * 16 + r) * C + lane * 8],              \
                  &Vs[(it) & 1][r * 256]);                                        \
    }                                                                             \
  }
  CP_STAGE(0)
#pragma unroll
  for (int it = 0; it < 10; ++it) {
    if (it < 9) CP_STAGE(it + 1)
    if (it < 9) { asm volatile("s_waitcnt vmcnt(4)" ::: "memory"); }
    else        { asm volatile("s_waitcnt vmcnt(0)" ::: "memory"); }
    __builtin_amdgcn_s_barrier();  // stage(it) visible to all waves
    const u16* Kc = Ks[it & 1];
    const u16* Vc = Vs[it & 1];
#pragma unroll
    for (int hh = 0; hh < 2; ++hh) {
      const int h = wave * 2 + hh;
#pragma unroll
      for (int l = 0; l < 16; ++l) {
        ushort4 ku = *(const ushort4*)&Kc[l * 256 + h * 32 + k4];
        ushort4 vu = *(const ushort4*)&Vc[l * 256 + h * 32 + v8 * 4];
        float ek[4] = {__expf(bf2f(ku.x)), __expf(bf2f(ku.y)),
                       __expf(bf2f(ku.z)), __expf(bf2f(ku.w))};
        float vf[4] = {bf2f(vu.x), bf2f(vu.y), bf2f(vu.z), bf2f(vu.w)};
#pragma unroll
        for (int i = 0; i < 4; ++i)
#pragma unroll
          for (int j = 0; j < 4; ++j) acc[hh][i][j] = fmaf(ek[i], vf[j], acc[hh][i][j]);
        if (v8 == 0)
#pragma unroll
          for (int i = 0; i < 4; ++i) ssum[hh][i] += ek[i];
      }
    }
    __builtin_amdgcn_s_barrier();  // compute(it) done before its buffer is restaged
  }
#undef CP_STAGE

#pragma unroll
  for (int hh = 0; hh < 2; ++hh) {
    const int h = wave * 2 + hh;
    const size_t pb = ((size_t)seg * NH + n * 8 + h) * 1024;
#pragma unroll
    for (int i = 0; i < 4; ++i)
#pragma unroll
      for (int j = 0; j < 4; ++j)
        pctx[pb + (size_t)(k4 + i) * 32 + v8 * 4 + j] = acc[hh][i][j];
    if (v8 == 0) {
      const size_t sb = ((size_t)seg * NH + n * 8 + h) * 32;
#pragma unroll
      for (int i = 0; i < 4; ++i) psum[sb + k4 + i] = ssum[hh][i];
    }
  }
}

// ---------------- reduce partials + normalize: ctx = (sum pctx) / (sum psum) ----------------
__global__ __launch_bounds__(256) void ctx_reduce(const float* __restrict__ pctx,
    const float* __restrict__ psum, float* __restrict__ ctx) {
  const int idx = blockIdx.x * 256 + threadIdx.x;  // < NH*1024
  const int nh = idx >> 10, e = idx & 1023, k = e >> 5;
  float s = 0.f, ss = 0.f;
  for (int g = 0; g < SEG; ++g) {
    s += pctx[(size_t)(g * NH + nh) * 1024 + e];
    ss += psum[(size_t)(g * NH + nh) * 32 + k];
  }
  ctx[idx] = s / ss;
}

// ---------------- fuse: M_n[o, h*32+k] = sum_v Wr[o,h*32+v]*ctx[n,h,k,v], bf16 ----------------
__global__ __launch_bounds__(256) void mfuse(const float* __restrict__ Wr,
    const float* __restrict__ ctx, u16* __restrict__ M) {
  const int idx = blockIdx.x * 256 + threadIdx.x;  // < NB*C*C
  const int hk = idx & 255;
  const int o = (idx >> 8) & 255;
  const int n = idx >> 16;
  const int h = hk >> 5, k = hk & 31;
  const float* wr = Wr + (size_t)o * C + h * HC;
  const float* cx = ctx + ((size_t)(n * HEADS + h) * HC + k) * HC;
  float s = 0.f;
#pragma unroll
  for (int v = 0; v < HC; ++v) s = fmaf(wr[v], cx[v], s);
  M[idx] = f2bf(s);
}

// ---- out[co][l] = sum_k M[co][k]*softmaxQ[l][k] + br[co] + Xq[co][l], fp32 ----
// Block: 64 l x 256 co. Q staged+softmaxed ONCE into persistent LDS panel;
// M tile double-buffered, single raw barrier per k-step,
// M staging overlapped under the MFMA phase.
__global__ __launch_bounds__(256) void out_fused(const u16* __restrict__ Qt,
    const u16* __restrict__ Mb, const float* __restrict__ br,
    const float* __restrict__ Xq, float* __restrict__ out) {
  __shared__ __align__(16) u16 Qp[64 * QPP];     // softmaxed Q, [l][k]
  __shared__ __align__(16) u16 As[2][128 * 32];  // M tile [co][k], double-buffered
  const int n = blockIdx.y, l0 = blockIdx.x * 64;
  const int t = threadIdx.x, lane = t & 63, wave = t >> 6;
  const int fr = lane & 15, q = lane >> 4;
  const int wcoL = (wave >> 1) * 64, wl = (wave & 1) * 32;
  const int srow = t >> 2, scol = (t & 3) * 8;
  const u16* QtN = Qt + (size_t)n * LL * C;
  const u16* MbN = Mb + (size_t)n * C * C;

  // issue first M-tile stage early so it hides under the Q softmax phase
#pragma unroll
  for (int s = 0; s < 2; ++s)
    gload_lds16(&MbN[(size_t)(s * 64 + srow) * C + scol], &As[0][s * 2048 + wave * 512]);

#pragma unroll
  for (int p = 0; p < 2; ++p) {
    const int row = p * 32 + (t >> 3);
    const int g = t & 7;
    const uint4* src = (const uint4*)&QtN[(size_t)(l0 + row) * C + g * 32];
    uint4 u0 = src[0], u1 = src[1], u2 = src[2], u3 = src[3];
    float v[32];
    unpack8(u0, v); unpack8(u1, v + 8); unpack8(u2, v + 16); unpack8(u3, v + 24);
    float e[32], s = 0.f;
#pragma unroll
    for (int j = 0; j < 32; ++j) { e[j] = __expf(v[j]); s += e[j]; }
    const float r = 1.0f / s;
    uint4* drow = (uint4*)&Qp[row * QPP + g * 32];
#pragma unroll
    for (int b4 = 0; b4 < 4; ++b4) {
      union { uint4 u; u16 h[8]; } o;
#pragma unroll
      for (int j = 0; j < 8; ++j) o.h[j] = f2bf(e[b4 * 8 + j] * r);
      drow[b4] = o.u;
    }
  }
  asm volatile("s_waitcnt vmcnt(0) lgkmcnt(0)" ::: "memory");
  __builtin_amdgcn_s_barrier();
  __builtin_amdgcn_sched_barrier(0);

  f32x4 acc[2][4][2] = {};
#pragma unroll
  for (int it = 0; it < 16; ++it) {
    const int coh = it >> 3, k0 = (it & 7) * 32, cur = it & 1;
    if (it < 15) {
      const int nco = (it + 1) >> 3, nk0 = ((it + 1) & 7) * 32;
#pragma unroll
      for (int s = 0; s < 2; ++s)
        gload_lds16(&MbN[(size_t)(nco * 128 + s * 64 + srow) * C + nk0 + scol],
                    &As[cur ^ 1][s * 2048 + wave * 512]);
      __builtin_amdgcn_sched_barrier(0);
    }
    bf16x8 a[4], b[2];
#pragma unroll
    for (int i = 0; i < 4; ++i)
      a[i] = *(const bf16x8*)&As[cur][(wcoL + i * 16 + fr) * 32 + q * 8];
#pragma unroll
    for (int j = 0; j < 2; ++j)
      b[j] = *(const bf16x8*)&Qp[(wl + j * 16 + fr) * QPP + k0 + q * 8];
#pragma unroll
    for (int i = 0; i < 4; ++i)
#pragma unroll
      for (int j = 0; j < 2; ++j)
        acc[coh][i][j] = __builtin_amdgcn_mfma_f32_16x16x32_bf16(a[i], b[j], acc[coh][i][j], 0, 0, 0);
    if (it < 15) {
      asm volatile("s_waitcnt vmcnt(0) lgkmcnt(0)" ::: "memory");
      __builtin_amdgcn_s_barrier();
      __builtin_amdgcn_sched_barrier(0);
    }
  }

  const float* XqN = Xq + (size_t)n * C * LL;
  float* On = out + (size_t)n * C * LL;
#pragma unroll
  for (int coh = 0; coh < 2; ++coh)
#pragma unroll
    for (int i = 0; i < 4; ++i)
#pragma unroll
      for (int r = 0; r < 4; ++r) {
        const int co = coh * 128 + wcoL + i * 16 + q * 4 + r;
        const float bb = br[co];
#pragma unroll
        for (int j = 0; j < 2; ++j) {
          const int l = l0 + wl + j * 16 + fr;
          const size_t off = (size_t)co * LL + l;
          On[off] = acc[coh][i][j][r] + bb + XqN[off];
        }
      }
}

extern "C" void kernel_launch(void* const* d_in, const int* in_sizes, int n_in,
                              void* d_out, int out_size, void* d_ws, size_t ws_size,
                              hipStream_t stream) {
  const float* Xq = (const float*)d_in[0];
  const float* Xk = (const float*)d_in[1];
  const float* Xv = (const float*)d_in[2];
  const float* Wq = (const float*)d_in[3];
  const float* bq = (const float*)d_in[4];
  const float* Wk = (const float*)d_in[5];
  const float* bk = (const float*)d_in[6];
  const float* Wv = (const float*)d_in[7];
  const float* bv = (const float*)d_in[8];
  const float* Wr = (const float*)d_in[9];
  const float* br = (const float*)d_in[10];
  float* out = (float*)d_out;

  char* ws = (char*)d_ws;
  const size_t nelem = (size_t)NB * LL * C;  // per [L][C] bf16 buffer
  u16* Qt = (u16*)ws;
  u16* Kt = (u16*)(ws + nelem * 2);
  u16* Vt = (u16*)(ws + nelem * 4);
  char* p = ws + nelem * 6;
  u16* Wqb = (u16*)p; p += C * C * 2;
  u16* Wkb = (u16*)p; p += C * C * 2;
  u16* Wvb = (u16*)p; p += C * C * 2;
  float* pctx = (float*)p; p += (size_t)SEG * NH * HC * HC * 4;
  float* psum = (float*)p; p += (size_t)SEG * NH * HC * 4;
  float* ctx = (float*)p;  p += (size_t)NH * HC * HC * 4;
  u16* Mb = (u16*)p;
  // workspace use identical to rounds 0-4 (~91 MB)

  WcvtArgs wa;
  wa.W[0] = Wq; wa.W[1] = Wk; wa.W[2] = Wv;
  wa.Wb[0] = Wqb; wa.Wb[1] = Wkb; wa.Wb[2] = Wvb;
  wcvt<<<96, 256, 0, stream>>>(wa);

  PFArgs pa;
  pa.X[0] = Xq; pa.X[1] = Xk; pa.X[2] = Xv;
  pa.Wb[0] = Wqb; pa.Wb[1] = Wkb; pa.Wb[2] = Wvb;
  pa.bias[0] = bq; pa.bias[1] = bk; pa.bias[2] = bv;
  pa.P[0] = Qt; pa.P[1] = Kt; pa.P[2] = Vt;
  proj_fused<<<dim3(100, 24), 256, 0, stream>>>(pa);

  ctx_part<<<dim3(SEG, NB), 256, 0, stream>>>(Kt, Vt, pctx, psum);
  ctx_reduce<<<NH * HC * HC / 256, 256, 0, stream>>>(pctx, psum, ctx);
  mfuse<<<NB * C * C / 256, 256, 0, stream>>>(Wr, ctx, Mb);
  out_fused<<<dim3(100, NB), 256, 0, stream>>>(Qt, Mb, br, Xq, out);
}

// Round 10
// 334.194 us; speedup vs baseline: 3.2889x; 3.2889x over previous
//
#include <hip/hip_runtime.h>
#include <hip/hip_bf16.h>

#define NB 8
#define C 256
#define LL 6400
#define HEADS 8
#define HC 32
#define NH 64      // NB*HEADS
#define SEG 40     // ctx l-segments
#define SL 160     // LL / SEG
#define QPP 264    // out Q-panel pitch (u16)

typedef unsigned short u16;
typedef unsigned int u32;
typedef __attribute__((ext_vector_type(8))) short bf16x8;
typedef __attribute__((ext_vector_type(4))) float f32x4;

typedef __attribute__((address_space(1))) const u32 ga_u32;
typedef __attribute__((address_space(3))) u32 ls_u32;

__device__ __forceinline__ void gload_lds16(const u16* g, u16* l) {
  __builtin_amdgcn_global_load_lds((ga_u32*)g, (ls_u32*)l, 16, 0, 0);
}

__device__ __forceinline__ float bf2f(u32 u) { return __uint_as_float(u << 16); }
__device__ __forceinline__ u16 f2bf(float f) {
  __hip_bfloat16 h = __float2bfloat16(f);
  return *(u16*)&h;
}
__device__ __forceinline__ void unpack8(uint4 u, float* f) {
  f[0] = bf2f(u.x & 0xffffu); f[1] = bf2f(u.x >> 16);
  f[2] = bf2f(u.y & 0xffffu); f[3] = bf2f(u.y >> 16);
  f[4] = bf2f(u.z & 0xffffu); f[5] = bf2f(u.z >> 16);
  f[6] = bf2f(u.w & 0xffffu); f[7] = bf2f(u.w >> 16);
}

struct WcvtArgs { const float* W[3]; u16* Wb[3]; };
struct PFArgs { const float* X[3]; const u16* Wb[3]; const float* bias[3]; u16* P[3]; };

// ---- W fp32 -> bf16, chunk-swizzled within each 32-c window: v ^= (co>>1)&3 ----
// (verified) Kills the 8-way Bs bank conflict of the linear layout.
__global__ __launch_bounds__(256) void wcvt(WcvtArgs a) {
  const int idx = blockIdx.x * 256 + threadIdx.x;  // < 3*256*32 chunks
  const int which = idx >> 13, r = idx & 8191;
  const int co = r >> 5, c8 = r & 31;
  const float* src = a.W[which] + co * 256 + c8 * 8;
  float4 v0 = *(const float4*)src, v1 = *(const float4*)(src + 4);
  union { bf16x8 v; u16 h[8]; } o;
  o.h[0] = f2bf(v0.x); o.h[1] = f2bf(v0.y); o.h[2] = f2bf(v0.z); o.h[3] = f2bf(v0.w);
  o.h[4] = f2bf(v1.x); o.h[5] = f2bf(v1.y); o.h[6] = f2bf(v1.z); o.h[7] = f2bf(v1.w);
  const int p = (c8 & ~3) | ((c8 & 3) ^ ((co >> 1) & 3));
  *(bf16x8*)&a.Wb[which][co * 256 + p * 8] = o.v;
}

// ------- proj (x3, transpose fused IN-LDS): Pt[l][co] = sum_c X[c][l]*W[co][c]+b -------
// R9 structure kept: per-wave pipelined preamble (zero barriers, counted
// vmcnt(2)), k-loop/W-path/epilogue verified since R7.
__global__ __launch_bounds__(256, 2) void proj_fused(PFArgs args) {
  __shared__ __align__(16) float Xs[2][32 * 64];  // eighth stage dbuf, 2x8 KB
  __shared__ __align__(16) u16 Ap[64 * 256];      // A panel [l][c] bf16, 32 KB; epilogue reuses
  __shared__ __align__(16) u16 Bs[2][256 * 32];   // W dbuf, 32 KB
  const int which = blockIdx.y >> 3, n = blockIdx.y & 7;
  const int l0 = blockIdx.x * 64;
  const int t = threadIdx.x;
  const int lane = t & 63, wave = t >> 6;
  const int fr = lane & 15, q = lane >> 4;
  const int wl = (wave & 1) * 32, wco = (wave >> 1) * 128;
  const int srow = t >> 2, scol = (t & 3) * 8;  // B staging coords
  const float* X = args.X[which] + (size_t)n * C * LL;
  const u16* Wb = args.Wb[which];
  const int xr = lane >> 4, xc = (lane & 15) * 4;  // X stage per-lane coords

  // B tile 0 (oldest VM ops; forced complete by the first preamble vmcnt)
#pragma unroll
  for (int s = 0; s < 4; ++s)
    gload_lds16(&Wb[(size_t)(s * 64 + srow) * C + scol], &Bs[0][s * 2048 + wave * 512]);

  // ---- preamble: 8 eighths, per-wave pipelined, ZERO barriers ----
#define PF_STAGE(e)                                                                  \
  {                                                                                  \
    _Pragma("unroll")                                                                \
    for (int s = 0; s < 2; ++s)                                                      \
      gload_lds16((const u16*)&X[(size_t)(32 * (e) + wave * 8 + s * 4 + xr) * LL +   \
                                 l0 + xc],                                           \
                  (u16*)&Xs[(e) & 1][(wave * 8 + s * 4) * 64]);                      \
  }
  PF_STAGE(0)
  PF_STAGE(1)
#pragma unroll
  for (int e = 0; e < 8; ++e) {
    if (e < 7) { asm volatile("s_waitcnt vmcnt(2)" ::: "memory"); }
    else       { asm volatile("s_waitcnt vmcnt(0)" ::: "memory"); }
    // transpose own 8 rows of eighth e: chunk cb = 4e + wave
    float v[8];
#pragma unroll
    for (int ei = 0; ei < 8; ++ei) v[ei] = Xs[e & 1][(wave * 8 + ei) * 64 + lane];
    union { uint4 u; u32 w[4]; } pk;
#pragma unroll
    for (int p = 0; p < 4; ++p)
      pk.w[p] = (u32)f2bf(v[2 * p]) | ((u32)f2bf(v[2 * p + 1]) << 16);
    const int cb = e * 4 + wave;
    *(uint4*)&Ap[lane * 256 + ((cb ^ (lane & 7)) * 8)] = pk.u;
    if (e < 6) {
      // own ds_reads of Xs[e&1] retired before restaging it (rule #18 fence)
      asm volatile("s_waitcnt lgkmcnt(0)" ::: "memory");
      __builtin_amdgcn_sched_barrier(0);
      PF_STAGE(e + 2)
    }
  }
#undef PF_STAGE
  __syncthreads();  // Ap + Bs[0] visible to all waves

  // ---- k-loop: identical to R8 (verified) ----
  f32x4 acc[2][8] = {};
  const int sco = (fr >> 1) & 3;  // W chunk swizzle key
#pragma unroll
  for (int kt = 0; kt < 8; ++kt) {
    if (kt < 7) {
#pragma unroll
      for (int s = 0; s < 4; ++s)
        gload_lds16(&Wb[(size_t)(s * 64 + srow) * C + (kt + 1) * 32 + scol],
                    &Bs[(kt + 1) & 1][s * 2048 + wave * 512]);
    }
    bf16x8 a[2];
#pragma unroll
    for (int i = 0; i < 2; ++i) {
      const int row = wl + i * 16 + fr;
      a[i] = *(const bf16x8*)&Ap[row * 256 + (((kt * 4 + q) ^ (row & 7)) * 8)];
    }
#pragma unroll
    for (int j = 0; j < 8; ++j) {
      bf16x8 b = *(const bf16x8*)&Bs[kt & 1][(wco + j * 16 + fr) * 32 + ((q ^ sco) * 8)];
#pragma unroll
      for (int i = 0; i < 2; ++i)
        acc[i][j] = __builtin_amdgcn_mfma_f32_16x16x32_bf16(a[i], b, acc[i][j], 0, 0, 0);
    }
    __syncthreads();  // next Bs tile complete; buffers ping-pong safely
  }

  // ---- epilogue: identical to R8 (verified), reuse Ap ----
  const float* bias = args.bias[which];
  u16* P = args.P[which] + (size_t)n * LL * C;
  float bb[8];
#pragma unroll
  for (int j = 0; j < 8; ++j) bb[j] = bias[wco + j * 16 + fr];
#pragma unroll
  for (int i = 0; i < 2; ++i)
#pragma unroll
    for (int r = 0; r < 4; ++r) {
      const int lrow = wl + i * 16 + q * 4 + r;  // 0..63 block-local
#pragma unroll
      for (int j = 0; j < 8; ++j)
        Ap[lrow * 256 + wco + j * 16 + fr] = f2bf(acc[i][j][r] + bb[j]);
    }
  __syncthreads();
  const int rg = t >> 5, ch = t & 31;  // row group, 16B chunk
#pragma unroll
  for (int s = 0; s < 8; ++s) {
    const int row = rg * 8 + s;
    bf16x8 vrow = *(const bf16x8*)&Ap[row * 256 + ch * 8];
    *(bf16x8*)&P[(size_t)(l0 + row) * C + ch * 8] = vrow;  // 512B/row, full lines
  }
}

// -------- ctx partials (one pass, no-max softmax): pctx += exp(K)[l,k]*V[l,v] --------
// grid (SEG, NB). K/V dbuf, per-wave counted vmcnt(4), raw barriers.
// R9 REGRESSION ROOT CAUSE: #pragma unroll flattened the 10-iter loop (each
// iter: 640 LDS loads + 512 fmaf + 128 exp) -> compiler hoisted across iters,
// VGPR hit the 256 cap, spilled working set to scratch: WRITE_SIZE 891 MB vs
// 11 MB ideal, 852us. Fix: FORCE the loop rolled (#pragma unroll 1). The
// pipeline structure itself is correct and stays.
__global__ __launch_bounds__(256) void ctx_part(const u16* __restrict__ Kt,
    const u16* __restrict__ Vt, float* __restrict__ pctx, float* __restrict__ psum) {
  __shared__ __align__(16) u16 Ks[2][16 * 256];
  __shared__ __align__(16) u16 Vs[2][16 * 256];
  const int seg = blockIdx.x, n = blockIdx.y;
  const int t = threadIdx.x, lane = t & 63, wave = t >> 6;
  const int l0 = seg * SL;
  const u16* KtN = Kt + (size_t)n * LL * C;
  const u16* VtN = Vt + (size_t)n * LL * C;
  const int k4 = (lane & 7) * 4, v8 = lane >> 3;
  float acc[2][4][4] = {};
  float ssum[2][4] = {};

#define CP_STAGE(it)                                                              \
  {                                                                               \
    _Pragma("unroll")                                                             \
    for (int i = 0; i < 2; ++i) {                                                 \
      const int r = wave * 4 + i * 2;                                             \
      gload_lds16(&KtN[(size_t)(l0 + (it) * 16 + r) * C + lane * 8],              \
                  &Ks[(it) & 1][r * 256]);                                        \
      gload_lds16(&VtN[(size_t)(l0 + (it) * 16 + r) * C + lane * 8],              \
                  &Vs[(it) & 1][r * 256]);                                        \
    }                                                                             \
  }
  CP_STAGE(0)
#pragma unroll 1
  for (int it = 0; it < 10; ++it) {
    if (it < 9) {
      CP_STAGE(it + 1)
      asm volatile("s_waitcnt vmcnt(4)" ::: "memory");  // stage(it) done, it+1 flying
    } else {
      asm volatile("s_waitcnt vmcnt(0)" ::: "memory");
    }
    __builtin_amdgcn_s_barrier();  // stage(it) visible to all waves
    const u16* Kc = Ks[it & 1];
    const u16* Vc = Vs[it & 1];
#pragma unroll
    for (int hh = 0; hh < 2; ++hh) {
      const int h = wave * 2 + hh;
#pragma unroll
      for (int l = 0; l < 16; ++l) {
        ushort4 ku = *(const ushort4*)&Kc[l * 256 + h * 32 + k4];
        ushort4 vu = *(const ushort4*)&Vc[l * 256 + h * 32 + v8 * 4];
        float ek[4] = {__expf(bf2f(ku.x)), __expf(bf2f(ku.y)),
                       __expf(bf2f(ku.z)), __expf(bf2f(ku.w))};
        float vf[4] = {bf2f(vu.x), bf2f(vu.y), bf2f(vu.z), bf2f(vu.w)};
#pragma unroll
        for (int i = 0; i < 4; ++i)
#pragma unroll
          for (int j = 0; j < 4; ++j) acc[hh][i][j] = fmaf(ek[i], vf[j], acc[hh][i][j]);
        if (v8 == 0)
#pragma unroll
          for (int i = 0; i < 4; ++i) ssum[hh][i] += ek[i];
      }
    }
    __builtin_amdgcn_s_barrier();  // compute(it) done before its buffer is restaged
  }
#undef CP_STAGE

#pragma unroll
  for (int hh = 0; hh < 2; ++hh) {
    const int h = wave * 2 + hh;
    const size_t pb = ((size_t)seg * NH + n * 8 + h) * 1024;
#pragma unroll
    for (int i = 0; i < 4; ++i)
#pragma unroll
      for (int j = 0; j < 4; ++j)
        pctx[pb + (size_t)(k4 + i) * 32 + v8 * 4 + j] = acc[hh][i][j];
    if (v8 == 0) {
      const size_t sb = ((size_t)seg * NH + n * 8 + h) * 32;
#pragma unroll
      for (int i = 0; i < 4; ++i) psum[sb + k4 + i] = ssum[hh][i];
    }
  }
}

// ---------------- reduce partials + normalize: ctx = (sum pctx) / (sum psum) ----------------
__global__ __launch_bounds__(256) void ctx_reduce(const float* __restrict__ pctx,
    const float* __restrict__ psum, float* __restrict__ ctx) {
  const int idx = blockIdx.x * 256 + threadIdx.x;  // < NH*1024
  const int nh = idx >> 10, e = idx & 1023, k = e >> 5;
  float s = 0.f, ss = 0.f;
  for (int g = 0; g < SEG; ++g) {
    s += pctx[(size_t)(g * NH + nh) * 1024 + e];
    ss += psum[(size_t)(g * NH + nh) * 32 + k];
  }
  ctx[idx] = s / ss;
}

// ---------------- fuse: M_n[o, h*32+k] = sum_v Wr[o,h*32+v]*ctx[n,h,k,v], bf16 ----------------
__global__ __launch_bounds__(256) void mfuse(const float* __restrict__ Wr,
    const float* __restrict__ ctx, u16* __restrict__ M) {
  const int idx = blockIdx.x * 256 + threadIdx.x;  // < NB*C*C
  const int hk = idx & 255;
  const int o = (idx >> 8) & 255;
  const int n = idx >> 16;
  const int h = hk >> 5, k = hk & 31;
  const float* wr = Wr + (size_t)o * C + h * HC;
  const float* cx = ctx + ((size_t)(n * HEADS + h) * HC + k) * HC;
  float s = 0.f;
#pragma unroll
  for (int v = 0; v < HC; ++v) s = fmaf(wr[v], cx[v], s);
  M[idx] = f2bf(s);
}

// ---- out[co][l] = sum_k M[co][k]*softmaxQ[l][k] + br[co] + Xq[co][l], fp32 ----
// Block: 64 l x 256 co. Q staged+softmaxed ONCE into persistent LDS panel;
// M tile double-buffered, single raw barrier per k-step,
// M staging overlapped under the MFMA phase.
__global__ __launch_bounds__(256) void out_fused(const u16* __restrict__ Qt,
    const u16* __restrict__ Mb, const float* __restrict__ br,
    const float* __restrict__ Xq, float* __restrict__ out) {
  __shared__ __align__(16) u16 Qp[64 * QPP];     // softmaxed Q, [l][k]
  __shared__ __align__(16) u16 As[2][128 * 32];  // M tile [co][k], double-buffered
  const int n = blockIdx.y, l0 = blockIdx.x * 64;
  const int t = threadIdx.x, lane = t & 63, wave = t >> 6;
  const int fr = lane & 15, q = lane >> 4;
  const int wcoL = (wave >> 1) * 64, wl = (wave & 1) * 32;
  const int srow = t >> 2, scol = (t & 3) * 8;
  const u16* QtN = Qt + (size_t)n * LL * C;
  const u16* MbN = Mb + (size_t)n * C * C;

  // issue first M-tile stage early so it hides under the Q softmax phase
#pragma unroll
  for (int s = 0; s < 2; ++s)
    gload_lds16(&MbN[(size_t)(s * 64 + srow) * C + scol], &As[0][s * 2048 + wave * 512]);

#pragma unroll
  for (int p = 0; p < 2; ++p) {
    const int row = p * 32 + (t >> 3);
    const int g = t & 7;
    const uint4* src = (const uint4*)&QtN[(size_t)(l0 + row) * C + g * 32];
    uint4 u0 = src[0], u1 = src[1], u2 = src[2], u3 = src[3];
    float v[32];
    unpack8(u0, v); unpack8(u1, v + 8); unpack8(u2, v + 16); unpack8(u3, v + 24);
    float e[32], s = 0.f;
#pragma unroll
    for (int j = 0; j < 32; ++j) { e[j] = __expf(v[j]); s += e[j]; }
    const float r = 1.0f / s;
    uint4* drow = (uint4*)&Qp[row * QPP + g * 32];
#pragma unroll
    for (int b4 = 0; b4 < 4; ++b4) {
      union { uint4 u; u16 h[8]; } o;
#pragma unroll
      for (int j = 0; j < 8; ++j) o.h[j] = f2bf(e[b4 * 8 + j] * r);
      drow[b4] = o.u;
    }
  }
  asm volatile("s_waitcnt vmcnt(0) lgkmcnt(0)" ::: "memory");
  __builtin_amdgcn_s_barrier();
  __builtin_amdgcn_sched_barrier(0);

  f32x4 acc[2][4][2] = {};
#pragma unroll
  for (int it = 0; it < 16; ++it) {
    const int coh = it >> 3, k0 = (it & 7) * 32, cur = it & 1;
    if (it < 15) {
      const int nco = (it + 1) >> 3, nk0 = ((it + 1) & 7) * 32;
#pragma unroll
      for (int s = 0; s < 2; ++s)
        gload_lds16(&MbN[(size_t)(nco * 128 + s * 64 + srow) * C + nk0 + scol],
                    &As[cur ^ 1][s * 2048 + wave * 512]);
      __builtin_amdgcn_sched_barrier(0);
    }
    bf16x8 a[4], b[2];
#pragma unroll
    for (int i = 0; i < 4; ++i)
      a[i] = *(const bf16x8*)&As[cur][(wcoL + i * 16 + fr) * 32 + q * 8];
#pragma unroll
    for (int j = 0; j < 2; ++j)
      b[j] = *(const bf16x8*)&Qp[(wl + j * 16 + fr) * QPP + k0 + q * 8];
#pragma unroll
    for (int i = 0; i < 4; ++i)
#pragma unroll
      for (int j = 0; j < 2; ++j)
        acc[coh][i][j] = __builtin_amdgcn_mfma_f32_16x16x32_bf16(a[i], b[j], acc[coh][i][j], 0, 0, 0);
    if (it < 15) {
      asm volatile("s_waitcnt vmcnt(0) lgkmcnt(0)" ::: "memory");
      __builtin_amdgcn_s_barrier();
      __builtin_amdgcn_sched_barrier(0);
    }
  }

  const float* XqN = Xq + (size_t)n * C * LL;
  float* On = out + (size_t)n * C * LL;
#pragma unroll
  for (int coh = 0; coh < 2; ++coh)
#pragma unroll
    for (int i = 0; i < 4; ++i)
#pragma unroll
      for (int r = 0; r < 4; ++r) {
        const int co = coh * 128 + wcoL + i * 16 + q * 4 + r;
        const float bb = br[co];
#pragma unroll
        for (int j = 0; j < 2; ++j) {
          const int l = l0 + wl + j * 16 + fr;
          const size_t off = (size_t)co * LL + l;
          On[off] = acc[coh][i][j][r] + bb + XqN[off];
        }
      }
}

extern "C" void kernel_launch(void* const* d_in, const int* in_sizes, int n_in,
                              void* d_out, int out_size, void* d_ws, size_t ws_size,
                              hipStream_t stream) {
  const float* Xq = (const float*)d_in[0];
  const float* Xk = (const float*)d_in[1];
  const float* Xv = (const float*)d_in[2];
  const float* Wq = (const float*)d_in[3];
  const float* bq = (const float*)d_in[4];
  const float* Wk = (const float*)d_in[5];
  const float* bk = (const float*)d_in[6];
  const float* Wv = (const float*)d_in[7];
  const float* bv = (const float*)d_in[8];
  const float* Wr = (const float*)d_in[9];
  const float* br = (const float*)d_in[10];
  float* out = (float*)d_out;

  char* ws = (char*)d_ws;
  const size_t nelem = (size_t)NB * LL * C;  // per [L][C] bf16 buffer
  u16* Qt = (u16*)ws;
  u16* Kt = (u16*)(ws + nelem * 2);
  u16* Vt = (u16*)(ws + nelem * 4);
  char* p = ws + nelem * 6;
  u16* Wqb = (u16*)p; p += C * C * 2;
  u16* Wkb = (u16*)p; p += C * C * 2;
  u16* Wvb = (u16*)p; p += C * C * 2;
  float* pctx = (float*)p; p += (size_t)SEG * NH * HC * HC * 4;
  float* psum = (float*)p; p += (size_t)SEG * NH * HC * 4;
  float* ctx = (float*)p;  p += (size_t)NH * HC * HC * 4;
  u16* Mb = (u16*)p;
  // workspace use identical to rounds 0-4 (~91 MB)

  WcvtArgs wa;
  wa.W[0] = Wq; wa.W[1] = Wk; wa.W[2] = Wv;
  wa.Wb[0] = Wqb; wa.Wb[1] = Wkb; wa.Wb[2] = Wvb;
  wcvt<<<96, 256, 0, stream>>>(wa);

  PFArgs pa;
  pa.X[0] = Xq; pa.X[1] = Xk; pa.X[2] = Xv;
  pa.Wb[0] = Wqb; pa.Wb[1] = Wkb; pa.Wb[2] = Wvb;
  pa.bias[0] = bq; pa.bias[1] = bk; pa.bias[2] = bv;
  pa.P[0] = Qt; pa.P[1] = Kt; pa.P[2] = Vt;
  proj_fused<<<dim3(100, 24), 256, 0, stream>>>(pa);

  ctx_part<<<dim3(SEG, NB), 256, 0, stream>>>(Kt, Vt, pctx, psum);
  ctx_reduce<<<NH * HC * HC / 256, 256, 0, stream>>>(pctx, psum, ctx);
  mfuse<<<NB * C * C / 256, 256, 0, stream>>>(Wr, ctx, Mb);
  out_fused<<<dim3(100, NB), 256, 0, stream>>>(Qt, Mb, br, Xq, out);
}